// Round 3
// baseline (272.064 us; speedup 1.0000x reference)
//
#include <hip/hip_runtime.h>
#include <math.h>

#define BATCH   32768
#define NCLS    1000
#define NC4     250              // 1000/4 float4 chunks per row
#define NBLOCKS 2048
#define NWAVES  (NBLOCKS * 4)    // 8192 waves
#define RPW     (BATCH / NWAVES) // 4 rows per wave

typedef const __attribute__((address_space(1))) unsigned int gu32;
typedef __attribute__((address_space(3)))       unsigned int lu32;

// counted vmcnt wait: never drain to 0 mid-pipeline (T4). "memory" clobber
// orders the surrounding DMA issues and ds_reads against this wait.
#define WAITVM(N) asm volatile("s_waitcnt vmcnt(" #N ")" ::: "memory")

// One transcendental per element: flip sign by target predicate, single
// __expf feeds either sn (t==0) or sp (t!=0).
__device__ __forceinline__ void acc4(float4 xv, int4 tv, float& sn, float& sp) {
    float e0 = __expf(tv.x == 0 ? xv.x : -xv.x);
    float e1 = __expf(tv.y == 0 ? xv.y : -xv.y);
    float e2 = __expf(tv.z == 0 ? xv.z : -xv.z);
    float e3 = __expf(tv.w == 0 ? xv.w : -xv.w);
    sn += (tv.x == 0) ? e0 : 0.0f;  sp += (tv.x == 0) ? 0.0f : e0;
    sn += (tv.y == 0) ? e1 : 0.0f;  sp += (tv.y == 0) ? 0.0f : e1;
    sn += (tv.z == 0) ? e2 : 0.0f;  sp += (tv.z == 0) ? 0.0f : e2;
    sn += (tv.w == 0) ? e3 : 0.0f;  sp += (tv.w == 0) ? 0.0f : e3;
}

// Wave-private async-DMA pipeline. Rounds 0-2 proved the register allocator
// collapses ANY register-staged pipeline to ~1 load in flight (VGPR 32/40/48,
// dur identical 99us, BW 2.65 TB/s << every ceiling => latency-bound).
// global_load_lds is the staging mechanism the allocator cannot collapse:
// zero VGPR cost, counted by vmcnt. Each wave owns a 4-slot LDS ring
// (slot = 1KB x + 1KB t = one 64-chunk pass), prefetch depth 3 => 6KB in
// flight per wave, no __syncthreads anywhere. 32KB LDS/block -> 5 blocks/CU
// -> 20 waves/CU -> ~120KB outstanding per CU (vs ~13KB before).
__global__ __launch_bounds__(256, 5) void lsep_row_kernel(
    const float* __restrict__ x,
    const int*   __restrict__ t,
    float* __restrict__ wave_out) {

    __shared__ __align__(16) char smem[4][4][2048];  // [wave][slot][1KB x | 1KB t]

    const int tid   = threadIdx.x;
    const int lane  = tid & 63;
    const int wv    = tid >> 6;
    const int gwave = blockIdx.x * 4 + wv;           // 0..NWAVES-1

    // pass p (p = r*4+q): row = gwave + r*NWAVES, chunks q*64+lane (q==3: 58 lanes)
    // DMA issues exactly 2 vmcnt items per pass (exec mask never empty).
    auto DMA = [&](int p) {
        const int q = p & 3;
        if (q < 3 || lane < 58) {
            const size_t row  = (size_t)gwave + (size_t)(p >> 2) * NWAVES;
            const size_t cidx = row * NC4 + (size_t)(q * 64 + lane);
            const float4* gx = (const float4*)x + cidx;
            const int4*   gt = (const int4*)t + cidx;
            char* sl = &smem[wv][p & 3][0];          // wave-uniform LDS base
            __builtin_amdgcn_global_load_lds((gu32*)gx, (lu32*)sl,          16, 0, 0);
            __builtin_amdgcn_global_load_lds((gu32*)gt, (lu32*)(sl + 1024), 16, 0, 0);
        }
    };

    auto PASS = [&](int p, float& sn, float& sp) {
        const int q = p & 3;
        if (q < 3 || lane < 58) {
            const char* sl = &smem[wv][p & 3][0];
            float4 xv = *(const float4*)(sl + lane * 16);
            int4   tv = *(const int4*)(sl + 1024 + lane * 16);
            acc4(xv, tv, sn, sp);
        }
    };

    float acc = 0.0f;

    auto REDUCE = [&](float sn, float sp) {
        #pragma unroll
        for (int off = 32; off > 0; off >>= 1) {
            sn += __shfl_down(sn, off, 64);
            sp += __shfl_down(sp, off, 64);
        }
        if (lane == 0) acc += sn * sp;
    };

    // prologue: 3 passes in flight (6 loads)
    DMA(0); DMA(1); DMA(2);

    float sn, sp;
    // row 0 — steady state: issue pass p+3, wait until only 6 newest remain
    sn = 0.f; sp = 0.f;
    DMA(3);  WAITVM(6); PASS(0, sn, sp);
    DMA(4);  WAITVM(6); PASS(1, sn, sp);
    DMA(5);  WAITVM(6); PASS(2, sn, sp);
    DMA(6);  WAITVM(6); PASS(3, sn, sp);
    REDUCE(sn, sp);
    // row 1
    sn = 0.f; sp = 0.f;
    DMA(7);  WAITVM(6); PASS(4, sn, sp);
    DMA(8);  WAITVM(6); PASS(5, sn, sp);
    DMA(9);  WAITVM(6); PASS(6, sn, sp);
    DMA(10); WAITVM(6); PASS(7, sn, sp);
    REDUCE(sn, sp);
    // row 2
    sn = 0.f; sp = 0.f;
    DMA(11); WAITVM(6); PASS(8, sn, sp);
    DMA(12); WAITVM(6); PASS(9, sn, sp);
    DMA(13); WAITVM(6); PASS(10, sn, sp);
    DMA(14); WAITVM(6); PASS(11, sn, sp);
    REDUCE(sn, sp);
    // row 3 — epilogue drains 6 -> 4 -> 2 -> 0
    sn = 0.f; sp = 0.f;
    DMA(15); WAITVM(6); PASS(12, sn, sp);
    WAITVM(4);          PASS(13, sn, sp);
    WAITVM(2);          PASS(14, sn, sp);
    WAITVM(0);          PASS(15, sn, sp);
    REDUCE(sn, sp);

    if (lane == 0) wave_out[gwave] = acc;
}

// Single block reduces NWAVES partials: 8 independent float4 loads per
// thread (fully unrolled), shuffle + LDS reduce, log1p.
__global__ __launch_bounds__(256) void lsep_reduce_kernel(
    const float* __restrict__ wave_out,
    float* __restrict__ out) {

    const int tid = threadIdx.x;
    const float4* r4 = (const float4*)wave_out;   // NWAVES/4 = 2048 float4

    float4 a[8];
    #pragma unroll
    for (int j = 0; j < 8; ++j)
        a[j] = r4[tid + 256 * j];

    float v = 0.0f;
    #pragma unroll
    for (int j = 0; j < 8; ++j)
        v += (a[j].x + a[j].y) + (a[j].z + a[j].w);

    #pragma unroll
    for (int off = 32; off > 0; off >>= 1)
        v += __shfl_down(v, off, 64);

    __shared__ float sv[4];
    const int wave = tid >> 6;
    const int lane = tid & 63;
    if (lane == 0) sv[wave] = v;
    __syncthreads();

    if (tid == 0) {
        float total = (sv[0] + sv[1]) + (sv[2] + sv[3]);
        out[0] = log1pf(total);
    }
}

extern "C" void kernel_launch(void* const* d_in, const int* in_sizes, int n_in,
                              void* d_out, int out_size, void* d_ws, size_t ws_size,
                              hipStream_t stream) {
    const float* x = (const float*)d_in[0];
    const int*   t = (const int*)d_in[1];
    float* out     = (float*)d_out;
    float* wave_ws = (float*)d_ws;   // NWAVES floats = 32 KB

    lsep_row_kernel<<<NBLOCKS, 256, 0, stream>>>(x, t, wave_ws);
    lsep_reduce_kernel<<<1, 256, 0, stream>>>(wave_ws, out);
}

// Round 4
// 268.327 us; speedup vs baseline: 1.0139x; 1.0139x over previous
//
#include <hip/hip_runtime.h>
#include <math.h>

#define BATCH   32768
#define NCLS    1000
#define NC4     250              // 1000/4 float4 chunks per row
#define NBLOCKS 2048
#define NWAVES  (NBLOCKS * 4)    // 8192 waves
#define RPW     (BATCH / NWAVES) // 4 rows per wave

// Inline-asm load: the register allocator cannot sink or collapse this the
// way it did to every source-level staging attempt (R0-R2: VGPR 32/40/48,
// ~1-4 loads in flight). asm volatile order is preserved among volatiles,
// so issue order == program order and vmcnt counting is exact.
#define GLOAD4(dst, ptr) \
    asm volatile("global_load_dwordx4 %0, %1, off" : "=v"(dst) : "v"(ptr) : "memory")

// Counted wait + sched_barrier(0): rule #18 — without the barrier, hipcc
// hoists register-only consumers above an inline-asm waitcnt.
#define WAITVM(N) do { \
    asm volatile("s_waitcnt vmcnt(" #N ")" ::: "memory"); \
    __builtin_amdgcn_sched_barrier(0); \
} while (0)

// One transcendental per element; w=0 kills the contribution of clamped
// tail lanes exactly (adds 0.0f, bit-exact vs branching them off).
__device__ __forceinline__ void acc4w(float4 xv, int4 tv, float w,
                                      float& sn, float& sp) {
    float e0 = w * __expf(tv.x == 0 ? xv.x : -xv.x);
    float e1 = w * __expf(tv.y == 0 ? xv.y : -xv.y);
    float e2 = w * __expf(tv.z == 0 ? xv.z : -xv.z);
    float e3 = w * __expf(tv.w == 0 ? xv.w : -xv.w);
    sn += (tv.x == 0) ? e0 : 0.0f;  sp += (tv.x == 0) ? 0.0f : e0;
    sn += (tv.y == 0) ? e1 : 0.0f;  sp += (tv.y == 0) ? 0.0f : e1;
    sn += (tv.z == 0) ? e2 : 0.0f;  sp += (tv.z == 0) ? 0.0f : e2;
    sn += (tv.w == 0) ? e3 : 0.0f;  sp += (tv.w == 0) ? 0.0f : e3;
}

// Decisive probe: VGPR-staged loads with asm-enforced depth-16 pipeline.
// Two row-slots (A/B) of 8 dwordx4 each; while row r is consumed, row r+1's
// 16 KB is in flight. No LDS, no barriers. __launch_bounds__(256,4) gives a
// 128-VGPR budget (16 waves/CU) for the 64 staging VGPRs.
__global__ __launch_bounds__(256, 4) void lsep_row_kernel(
    const float* __restrict__ x,
    const int*   __restrict__ t,
    float* __restrict__ wave_out) {

    const int tid   = threadIdx.x;
    const int lane  = tid & 63;
    const int gwave = blockIdx.x * 4 + (tid >> 6);   // 0..NWAVES-1

    // chunk 3 is partial (250 = 3*64 + 58): lanes 58-63 load chunk 249
    // (in-bounds dummy) and contribute 0 via w3.
    const int   cid3 = (lane < 58) ? (192 + lane) : 249;
    const float w3   = (lane < 58) ? 1.0f : 0.0f;

    const size_t rstep = (size_t)NWAVES * NC4;       // float4 stride per +NWAVES rows
    const float4* xp = (const float4*)x + (size_t)gwave * NC4;
    const int4*   tp = (const int4*)t + (size_t)gwave * NC4;

    float4 xa0, xa1, xa2, xa3, xb0, xb1, xb2, xb3;
    int4   ta0, ta1, ta2, ta3, tb0, tb1, tb2, tb3;

    // Issue one row's 8 loads: x-burst then t-burst (longer per-stream runs).
    #define ISSUE_A(r) do { const float4* xr = xp + (size_t)(r) * rstep; \
                            const int4*   tr = tp + (size_t)(r) * rstep; \
        GLOAD4(xa0, xr + lane); GLOAD4(xa1, xr + 64 + lane); \
        GLOAD4(xa2, xr + 128 + lane); GLOAD4(xa3, xr + cid3); \
        GLOAD4(ta0, tr + lane); GLOAD4(ta1, tr + 64 + lane); \
        GLOAD4(ta2, tr + 128 + lane); GLOAD4(ta3, tr + cid3); } while (0)
    #define ISSUE_B(r) do { const float4* xr = xp + (size_t)(r) * rstep; \
                            const int4*   tr = tp + (size_t)(r) * rstep; \
        GLOAD4(xb0, xr + lane); GLOAD4(xb1, xr + 64 + lane); \
        GLOAD4(xb2, xr + 128 + lane); GLOAD4(xb3, xr + cid3); \
        GLOAD4(tb0, tr + lane); GLOAD4(tb1, tr + 64 + lane); \
        GLOAD4(tb2, tr + 128 + lane); GLOAD4(tb3, tr + cid3); } while (0)

    float acc = 0.0f;
    float sn, sp;

    #define REDUCE() do { \
        _Pragma("unroll") \
        for (int off = 32; off > 0; off >>= 1) { \
            sn += __shfl_down(sn, off, 64); \
            sp += __shfl_down(sp, off, 64); \
        } \
        if (lane == 0) acc += sn * sp; \
    } while (0)

    // prologue: rows 0 and 1 in flight (16 loads, 16 KB/wave)
    ISSUE_A(0);
    ISSUE_B(1);

    // row 0: newest 8 outstanding = row1's -> row0 landed
    WAITVM(8);
    sn = 0.f; sp = 0.f;
    acc4w(xa0, ta0, 1.0f, sn, sp); acc4w(xa1, ta1, 1.0f, sn, sp);
    acc4w(xa2, ta2, 1.0f, sn, sp); acc4w(xa3, ta3, w3,  sn, sp);
    ISSUE_A(2);                    // refill slot A while reducing
    REDUCE();

    // row 1
    WAITVM(8);
    sn = 0.f; sp = 0.f;
    acc4w(xb0, tb0, 1.0f, sn, sp); acc4w(xb1, tb1, 1.0f, sn, sp);
    acc4w(xb2, tb2, 1.0f, sn, sp); acc4w(xb3, tb3, w3,  sn, sp);
    ISSUE_B(3);
    REDUCE();

    // row 2
    WAITVM(8);
    sn = 0.f; sp = 0.f;
    acc4w(xa0, ta0, 1.0f, sn, sp); acc4w(xa1, ta1, 1.0f, sn, sp);
    acc4w(xa2, ta2, 1.0f, sn, sp); acc4w(xa3, ta3, w3,  sn, sp);
    REDUCE();

    // row 3 — drain
    WAITVM(0);
    sn = 0.f; sp = 0.f;
    acc4w(xb0, tb0, 1.0f, sn, sp); acc4w(xb1, tb1, 1.0f, sn, sp);
    acc4w(xb2, tb2, 1.0f, sn, sp); acc4w(xb3, tb3, w3,  sn, sp);
    REDUCE();

    if (lane == 0) wave_out[gwave] = acc;

    #undef ISSUE_A
    #undef ISSUE_B
    #undef REDUCE
}

// Single block reduces NWAVES partials: 8 independent float4 loads per
// thread (fully unrolled), shuffle + LDS reduce, log1p.
__global__ __launch_bounds__(256) void lsep_reduce_kernel(
    const float* __restrict__ wave_out,
    float* __restrict__ out) {

    const int tid = threadIdx.x;
    const float4* r4 = (const float4*)wave_out;   // NWAVES/4 = 2048 float4

    float4 a[8];
    #pragma unroll
    for (int j = 0; j < 8; ++j)
        a[j] = r4[tid + 256 * j];

    float v = 0.0f;
    #pragma unroll
    for (int j = 0; j < 8; ++j)
        v += (a[j].x + a[j].y) + (a[j].z + a[j].w);

    #pragma unroll
    for (int off = 32; off > 0; off >>= 1)
        v += __shfl_down(v, off, 64);

    __shared__ float sv[4];
    const int wave = tid >> 6;
    const int lane = tid & 63;
    if (lane == 0) sv[wave] = v;
    __syncthreads();

    if (tid == 0) {
        float total = (sv[0] + sv[1]) + (sv[2] + sv[3]);
        out[0] = log1pf(total);
    }
}

extern "C" void kernel_launch(void* const* d_in, const int* in_sizes, int n_in,
                              void* d_out, int out_size, void* d_ws, size_t ws_size,
                              hipStream_t stream) {
    const float* x = (const float*)d_in[0];
    const int*   t = (const int*)d_in[1];
    float* out     = (float*)d_out;
    float* wave_ws = (float*)d_ws;   // NWAVES floats = 32 KB

    lsep_row_kernel<<<NBLOCKS, 256, 0, stream>>>(x, t, wave_ws);
    lsep_reduce_kernel<<<1, 256, 0, stream>>>(wave_ws, out);
}

// Round 5
// 244.985 us; speedup vs baseline: 1.1105x; 1.0953x over previous
//
#include <hip/hip_runtime.h>
#include <math.h>

#define BATCH   32768
#define NCLS    1000
#define NC4     250              // 1000/4 float4 chunks per row
#define NBLOCKS 2048
#define NWAVES  (NBLOCKS * 4)    // 8192 waves
#define RPW     (BATCH / NWAVES) // 4 rows per wave

// Inline-asm load with NT (non-temporal) cache policy: single-variable A/B
// vs round 4 (identical structure, plain loads, 98.1 us). Every line is
// touched exactly once -> allocation in L1/L2 is pure overhead; nt marks
// the lines evict-first/no-allocate. If the 2.67 TB/s wall has an
// allocation-policy component this recovers it; if it's fabric sector
// tracking, this is null and the roofline case is complete.
#define GLOAD4(dst, ptr) \
    asm volatile("global_load_dwordx4 %0, %1, off nt" : "=v"(dst) : "v"(ptr) : "memory")

// Counted wait + sched_barrier(0): rule #18 — without the barrier, hipcc
// hoists register-only consumers above an inline-asm waitcnt.
#define WAITVM(N) do { \
    asm volatile("s_waitcnt vmcnt(" #N ")" ::: "memory"); \
    __builtin_amdgcn_sched_barrier(0); \
} while (0)

// One transcendental per element; w=0 kills the contribution of clamped
// tail lanes exactly (adds 0.0f, bit-exact vs branching them off).
__device__ __forceinline__ void acc4w(float4 xv, int4 tv, float w,
                                      float& sn, float& sp) {
    float e0 = w * __expf(tv.x == 0 ? xv.x : -xv.x);
    float e1 = w * __expf(tv.y == 0 ? xv.y : -xv.y);
    float e2 = w * __expf(tv.z == 0 ? xv.z : -xv.z);
    float e3 = w * __expf(tv.w == 0 ? xv.w : -xv.w);
    sn += (tv.x == 0) ? e0 : 0.0f;  sp += (tv.x == 0) ? 0.0f : e0;
    sn += (tv.y == 0) ? e1 : 0.0f;  sp += (tv.y == 0) ? 0.0f : e1;
    sn += (tv.z == 0) ? e2 : 0.0f;  sp += (tv.z == 0) ? 0.0f : e2;
    sn += (tv.w == 0) ? e3 : 0.0f;  sp += (tv.w == 0) ? 0.0f : e3;
}

// Asm-enforced depth-16 pipeline (structure identical to round 4).
__global__ __launch_bounds__(256, 4) void lsep_row_kernel(
    const float* __restrict__ x,
    const int*   __restrict__ t,
    float* __restrict__ wave_out) {

    const int tid   = threadIdx.x;
    const int lane  = tid & 63;
    const int gwave = blockIdx.x * 4 + (tid >> 6);   // 0..NWAVES-1

    // chunk 3 is partial (250 = 3*64 + 58): lanes 58-63 load chunk 249
    // (in-bounds dummy) and contribute 0 via w3.
    const int   cid3 = (lane < 58) ? (192 + lane) : 249;
    const float w3   = (lane < 58) ? 1.0f : 0.0f;

    const size_t rstep = (size_t)NWAVES * NC4;       // float4 stride per +NWAVES rows
    const float4* xp = (const float4*)x + (size_t)gwave * NC4;
    const int4*   tp = (const int4*)t + (size_t)gwave * NC4;

    float4 xa0, xa1, xa2, xa3, xb0, xb1, xb2, xb3;
    int4   ta0, ta1, ta2, ta3, tb0, tb1, tb2, tb3;

    // Issue one row's 8 loads: x-burst then t-burst (longer per-stream runs).
    #define ISSUE_A(r) do { const float4* xr = xp + (size_t)(r) * rstep; \
                            const int4*   tr = tp + (size_t)(r) * rstep; \
        GLOAD4(xa0, xr + lane); GLOAD4(xa1, xr + 64 + lane); \
        GLOAD4(xa2, xr + 128 + lane); GLOAD4(xa3, xr + cid3); \
        GLOAD4(ta0, tr + lane); GLOAD4(ta1, tr + 64 + lane); \
        GLOAD4(ta2, tr + 128 + lane); GLOAD4(ta3, tr + cid3); } while (0)
    #define ISSUE_B(r) do { const float4* xr = xp + (size_t)(r) * rstep; \
                            const int4*   tr = tp + (size_t)(r) * rstep; \
        GLOAD4(xb0, xr + lane); GLOAD4(xb1, xr + 64 + lane); \
        GLOAD4(xb2, xr + 128 + lane); GLOAD4(xb3, xr + cid3); \
        GLOAD4(tb0, tr + lane); GLOAD4(tb1, tr + 64 + lane); \
        GLOAD4(tb2, tr + 128 + lane); GLOAD4(tb3, tr + cid3); } while (0)

    float acc = 0.0f;
    float sn, sp;

    #define REDUCE() do { \
        _Pragma("unroll") \
        for (int off = 32; off > 0; off >>= 1) { \
            sn += __shfl_down(sn, off, 64); \
            sp += __shfl_down(sp, off, 64); \
        } \
        if (lane == 0) acc += sn * sp; \
    } while (0)

    // prologue: rows 0 and 1 in flight (16 loads, 16 KB/wave)
    ISSUE_A(0);
    ISSUE_B(1);

    // row 0: newest 8 outstanding = row1's -> row0 landed
    WAITVM(8);
    sn = 0.f; sp = 0.f;
    acc4w(xa0, ta0, 1.0f, sn, sp); acc4w(xa1, ta1, 1.0f, sn, sp);
    acc4w(xa2, ta2, 1.0f, sn, sp); acc4w(xa3, ta3, w3,  sn, sp);
    ISSUE_A(2);                    // refill slot A while reducing
    REDUCE();

    // row 1
    WAITVM(8);
    sn = 0.f; sp = 0.f;
    acc4w(xb0, tb0, 1.0f, sn, sp); acc4w(xb1, tb1, 1.0f, sn, sp);
    acc4w(xb2, tb2, 1.0f, sn, sp); acc4w(xb3, tb3, w3,  sn, sp);
    ISSUE_B(3);
    REDUCE();

    // row 2
    WAITVM(8);
    sn = 0.f; sp = 0.f;
    acc4w(xa0, ta0, 1.0f, sn, sp); acc4w(xa1, ta1, 1.0f, sn, sp);
    acc4w(xa2, ta2, 1.0f, sn, sp); acc4w(xa3, ta3, w3,  sn, sp);
    REDUCE();

    // row 3 — drain
    WAITVM(0);
    sn = 0.f; sp = 0.f;
    acc4w(xb0, tb0, 1.0f, sn, sp); acc4w(xb1, tb1, 1.0f, sn, sp);
    acc4w(xb2, tb2, 1.0f, sn, sp); acc4w(xb3, tb3, w3,  sn, sp);
    REDUCE();

    if (lane == 0) wave_out[gwave] = acc;

    #undef ISSUE_A
    #undef ISSUE_B
    #undef REDUCE
}

// Single block reduces NWAVES partials: 8 independent float4 loads per
// thread (fully unrolled), shuffle + LDS reduce, log1p.
__global__ __launch_bounds__(256) void lsep_reduce_kernel(
    const float* __restrict__ wave_out,
    float* __restrict__ out) {

    const int tid = threadIdx.x;
    const float4* r4 = (const float4*)wave_out;   // NWAVES/4 = 2048 float4

    float4 a[8];
    #pragma unroll
    for (int j = 0; j < 8; ++j)
        a[j] = r4[tid + 256 * j];

    float v = 0.0f;
    #pragma unroll
    for (int j = 0; j < 8; ++j)
        v += (a[j].x + a[j].y) + (a[j].z + a[j].w);

    #pragma unroll
    for (int off = 32; off > 0; off >>= 1)
        v += __shfl_down(v, off, 64);

    __shared__ float sv[4];
    const int wave = tid >> 6;
    const int lane = tid & 63;
    if (lane == 0) sv[wave] = v;
    __syncthreads();

    if (tid == 0) {
        float total = (sv[0] + sv[1]) + (sv[2] + sv[3]);
        out[0] = log1pf(total);
    }
}

extern "C" void kernel_launch(void* const* d_in, const int* in_sizes, int n_in,
                              void* d_out, int out_size, void* d_ws, size_t ws_size,
                              hipStream_t stream) {
    const float* x = (const float*)d_in[0];
    const int*   t = (const int*)d_in[1];
    float* out     = (float*)d_out;
    float* wave_ws = (float*)d_ws;   // NWAVES floats = 32 KB

    lsep_row_kernel<<<NBLOCKS, 256, 0, stream>>>(x, t, wave_ws);
    lsep_reduce_kernel<<<1, 256, 0, stream>>>(wave_ws, out);
}

// Round 6
// 244.695 us; speedup vs baseline: 1.1118x; 1.0012x over previous
//
#include <hip/hip_runtime.h>
#include <math.h>

#define BATCH   32768
#define NCLS    1000
#define NC4     250              // 1000/4 float4 chunks per row
#define NBLOCKS 2048
#define NWAVES  (NBLOCKS * 4)    // 8192 waves
#define RPW     (BATCH / NWAVES) // 4 rows per wave

// Round-5 established: 'nt' (non-temporal) on the streamed loads was worth
// -23 us total (row kernel 98 -> ~75 us). Mechanism: single-touch reads were
// allocating in L2/L3 and evicting the harness fill's dirty lines (65 MB of
// writebacks per dispatch in a read-only kernel). This round's single-variable
// A/B: add sc1 (device scope) on top of nt — the strongest L2-minimizing
// policy — on the otherwise identical proven structure.
#define GLOAD4(dst, ptr) \
    asm volatile("global_load_dwordx4 %0, %1, off sc1 nt" : "=v"(dst) : "v"(ptr) : "memory")

// Counted wait + sched_barrier(0): rule #18 — without the barrier, hipcc
// hoists register-only consumers above an inline-asm waitcnt.
#define WAITVM(N) do { \
    asm volatile("s_waitcnt vmcnt(" #N ")" ::: "memory"); \
    __builtin_amdgcn_sched_barrier(0); \
} while (0)

// One transcendental per element; w=0 kills the contribution of clamped
// tail lanes exactly (adds 0.0f, bit-exact vs branching them off).
__device__ __forceinline__ void acc4w(float4 xv, int4 tv, float w,
                                      float& sn, float& sp) {
    float e0 = w * __expf(tv.x == 0 ? xv.x : -xv.x);
    float e1 = w * __expf(tv.y == 0 ? xv.y : -xv.y);
    float e2 = w * __expf(tv.z == 0 ? xv.z : -xv.z);
    float e3 = w * __expf(tv.w == 0 ? xv.w : -xv.w);
    sn += (tv.x == 0) ? e0 : 0.0f;  sp += (tv.x == 0) ? 0.0f : e0;
    sn += (tv.y == 0) ? e1 : 0.0f;  sp += (tv.y == 0) ? 0.0f : e1;
    sn += (tv.z == 0) ? e2 : 0.0f;  sp += (tv.z == 0) ? 0.0f : e2;
    sn += (tv.w == 0) ? e3 : 0.0f;  sp += (tv.w == 0) ? 0.0f : e3;
}

// Asm-enforced depth-16 pipeline (structure identical to rounds 4/5).
__global__ __launch_bounds__(256, 4) void lsep_row_kernel(
    const float* __restrict__ x,
    const int*   __restrict__ t,
    float* __restrict__ wave_out) {

    const int tid   = threadIdx.x;
    const int lane  = tid & 63;
    const int gwave = blockIdx.x * 4 + (tid >> 6);   // 0..NWAVES-1

    // chunk 3 is partial (250 = 3*64 + 58): lanes 58-63 load chunk 249
    // (in-bounds dummy) and contribute 0 via w3.
    const int   cid3 = (lane < 58) ? (192 + lane) : 249;
    const float w3   = (lane < 58) ? 1.0f : 0.0f;

    const size_t rstep = (size_t)NWAVES * NC4;       // float4 stride per +NWAVES rows
    const float4* xp = (const float4*)x + (size_t)gwave * NC4;
    const int4*   tp = (const int4*)t + (size_t)gwave * NC4;

    float4 xa0, xa1, xa2, xa3, xb0, xb1, xb2, xb3;
    int4   ta0, ta1, ta2, ta3, tb0, tb1, tb2, tb3;

    // Issue one row's 8 loads: x-burst then t-burst (longer per-stream runs).
    #define ISSUE_A(r) do { const float4* xr = xp + (size_t)(r) * rstep; \
                            const int4*   tr = tp + (size_t)(r) * rstep; \
        GLOAD4(xa0, xr + lane); GLOAD4(xa1, xr + 64 + lane); \
        GLOAD4(xa2, xr + 128 + lane); GLOAD4(xa3, xr + cid3); \
        GLOAD4(ta0, tr + lane); GLOAD4(ta1, tr + 64 + lane); \
        GLOAD4(ta2, tr + 128 + lane); GLOAD4(ta3, tr + cid3); } while (0)
    #define ISSUE_B(r) do { const float4* xr = xp + (size_t)(r) * rstep; \
                            const int4*   tr = tp + (size_t)(r) * rstep; \
        GLOAD4(xb0, xr + lane); GLOAD4(xb1, xr + 64 + lane); \
        GLOAD4(xb2, xr + 128 + lane); GLOAD4(xb3, xr + cid3); \
        GLOAD4(tb0, tr + lane); GLOAD4(tb1, tr + 64 + lane); \
        GLOAD4(tb2, tr + 128 + lane); GLOAD4(tb3, tr + cid3); } while (0)

    float acc = 0.0f;
    float sn, sp;

    #define REDUCE() do { \
        _Pragma("unroll") \
        for (int off = 32; off > 0; off >>= 1) { \
            sn += __shfl_down(sn, off, 64); \
            sp += __shfl_down(sp, off, 64); \
        } \
        if (lane == 0) acc += sn * sp; \
    } while (0)

    // prologue: rows 0 and 1 in flight (16 loads, 16 KB/wave)
    ISSUE_A(0);
    ISSUE_B(1);

    // row 0: newest 8 outstanding = row1's -> row0 landed
    WAITVM(8);
    sn = 0.f; sp = 0.f;
    acc4w(xa0, ta0, 1.0f, sn, sp); acc4w(xa1, ta1, 1.0f, sn, sp);
    acc4w(xa2, ta2, 1.0f, sn, sp); acc4w(xa3, ta3, w3,  sn, sp);
    ISSUE_A(2);                    // refill slot A while reducing
    REDUCE();

    // row 1
    WAITVM(8);
    sn = 0.f; sp = 0.f;
    acc4w(xb0, tb0, 1.0f, sn, sp); acc4w(xb1, tb1, 1.0f, sn, sp);
    acc4w(xb2, tb2, 1.0f, sn, sp); acc4w(xb3, tb3, w3,  sn, sp);
    ISSUE_B(3);
    REDUCE();

    // row 2
    WAITVM(8);
    sn = 0.f; sp = 0.f;
    acc4w(xa0, ta0, 1.0f, sn, sp); acc4w(xa1, ta1, 1.0f, sn, sp);
    acc4w(xa2, ta2, 1.0f, sn, sp); acc4w(xa3, ta3, w3,  sn, sp);
    REDUCE();

    // row 3 — drain
    WAITVM(0);
    sn = 0.f; sp = 0.f;
    acc4w(xb0, tb0, 1.0f, sn, sp); acc4w(xb1, tb1, 1.0f, sn, sp);
    acc4w(xb2, tb2, 1.0f, sn, sp); acc4w(xb3, tb3, w3,  sn, sp);
    REDUCE();

    if (lane == 0) wave_out[gwave] = acc;

    #undef ISSUE_A
    #undef ISSUE_B
    #undef REDUCE
}

// Single block reduces NWAVES partials: 8 independent float4 loads per
// thread (fully unrolled), shuffle + LDS reduce, log1p.
__global__ __launch_bounds__(256) void lsep_reduce_kernel(
    const float* __restrict__ wave_out,
    float* __restrict__ out) {

    const int tid = threadIdx.x;
    const float4* r4 = (const float4*)wave_out;   // NWAVES/4 = 2048 float4

    float4 a[8];
    #pragma unroll
    for (int j = 0; j < 8; ++j)
        a[j] = r4[tid + 256 * j];

    float v = 0.0f;
    #pragma unroll
    for (int j = 0; j < 8; ++j)
        v += (a[j].x + a[j].y) + (a[j].z + a[j].w);

    #pragma unroll
    for (int off = 32; off > 0; off >>= 1)
        v += __shfl_down(v, off, 64);

    __shared__ float sv[4];
    const int wave = tid >> 6;
    const int lane = tid & 63;
    if (lane == 0) sv[wave] = v;
    __syncthreads();

    if (tid == 0) {
        float total = (sv[0] + sv[1]) + (sv[2] + sv[3]);
        out[0] = log1pf(total);
    }
}

extern "C" void kernel_launch(void* const* d_in, const int* in_sizes, int n_in,
                              void* d_out, int out_size, void* d_ws, size_t ws_size,
                              hipStream_t stream) {
    const float* x = (const float*)d_in[0];
    const int*   t = (const int*)d_in[1];
    float* out     = (float*)d_out;
    float* wave_ws = (float*)d_ws;   // NWAVES floats = 32 KB

    lsep_row_kernel<<<NBLOCKS, 256, 0, stream>>>(x, t, wave_ws);
    lsep_reduce_kernel<<<1, 256, 0, stream>>>(wave_ws, out);
}